// Round 2
// baseline (1275.678 us; speedup 1.0000x reference)
//
#include <hip/hip_runtime.h>
#include <hip/hip_bf16.h>

// Problem constants (from reference)
#define NP   3        // metapaths
#define NE   250000   // edges per metapath
#define NL   3        // metapath length
#define NT   8192     // targets
#define NN   100000   // nodes
#define IND  64       // in_dim
#define ND2  32       // in_dim/2 complex pairs
#define NH   8        // heads
#define NAD  128      // attn_vec_dim
#define NOD  64       // out_dim
#define NHD  512      // heads * in_dim
#define LALPHA 0.01f
#define NSEG (NP*NT)

// ws layout, in 4-byte words (total ~76 MB)
#define FLAG_W    0         // 1 int   : 1 = inputs are f32, 0 = inputs are bf16
#define FINALR_W  64        // 576 f32 : final_r [P][L][32][2]
#define BETAACC_W 1024      // 384 f32
#define BETA_W    1472      // 4 f32
#define COUNTS_W  2048      // 24576 int
#define OFFS_W    26624     // 24577 int
#define CURSOR_W  51264     // 24576 int
#define ELIST_W   75904     // 750000 int
#define FEATF_W   825920    // 6.4M f32 : features staged f32
#define ATTNF_W   7225920   // 1536 f32
#define FC1W_W    7227456   // 65536 f32
#define FC1B_W    7292992   // 128 f32
#define FC2W_W    7293120   // 128 f32
#define FCW_W     7293248   // 32768 f32
#define FCB_W     7326016   // 64 f32
#define RVECF_W   7326080   // 192 f32
#define OUTS_W    7326272   // 12.58M f32 : elu(outs) [P][NT][512]

__device__ __forceinline__ float bf2f(unsigned short u) {
    union { unsigned int i; float f; } c; c.i = ((unsigned int)u) << 16; return c.f;
}

// ---------------- kernel 0a: detect input dtype ----------------------------
// bf16 buffer of N(0,1) data: exponent fields cluster near 127 -> ~0 wild.
// f32 buffer: even ushorts are raw mantissa bits -> ~80% wild exponents.
__global__ void k_detect(const unsigned short* __restrict__ raw, int* __restrict__ flag) {
    if (threadIdx.x != 0 || blockIdx.x != 0) return;
    int wild = 0;
    for (int i = 0; i < 512; i++) {
        unsigned short u = raw[i];
        int e = (u >> 7) & 0xFF;
        if (u != 0 && (e < 0x60 || e > 0x90)) wild++;
    }
    *flag = (wild > 64) ? 1 : 0;
}

// ---------------- kernel 0b: convert any float tensor to f32 staging -------
__global__ void k_cvt(const void* __restrict__ src, float* __restrict__ dst, int n,
                      const int* __restrict__ flag) {
    int i = blockIdx.x * blockDim.x + threadIdx.x;
    if (i >= n) return;
    if (*flag) dst[i] = ((const float*)src)[i];
    else       dst[i] = bf2f(((const unsigned short*)src)[i]);
}

// ---------------- kernel 1: final rotation vectors -------------------------
__global__ void k_finalr(const float* __restrict__ r_vec, float* __restrict__ ws) {
    int k = threadIdx.x;
    if (k >= NP * ND2) return;
    int p = k / ND2, j = k % ND2;
    float re = r_vec[(p * ND2 + j) * 2 + 0];
    float im = r_vec[(p * ND2 + j) * 2 + 1];
    float inv = rsqrtf(re * re + im * im);
    float nre = re * inv, nim = im * inv;
    // ETYPES[p] = [2p, 2p+1]; r_full[2p] = r_norm, r_full[2p+1] = conj(r_norm)
    // f[2] = (1,0); f[1] = cmul(f[2], conj(r)); f[0] = cmul(f[1], r)
    float f2r = 1.f, f2i = 0.f;
    float f1r = nre, f1i = -nim;
    float f0r = f1r * nre - f1i * nim;
    float f0i = f1r * nim + f1i * nre;
    float* fr = ws + FINALR_W + p * NL * ND2 * 2;
    fr[(0 * ND2 + j) * 2 + 0] = f0r; fr[(0 * ND2 + j) * 2 + 1] = f0i;
    fr[(1 * ND2 + j) * 2 + 0] = f1r; fr[(1 * ND2 + j) * 2 + 1] = f1i;
    fr[(2 * ND2 + j) * 2 + 0] = f2r; fr[(2 * ND2 + j) * 2 + 1] = f2i;
}

// ---------------- kernel 2: per-segment edge counts ------------------------
__global__ void k_count(const int* __restrict__ dst, int* __restrict__ counts) {
    int id = blockIdx.x * blockDim.x + threadIdx.x;
    if (id >= NP * NE) return;
    int p = id / NE;
    atomicAdd(&counts[p * NT + dst[id]], 1);
}

// ---------------- kernel 3: exclusive scan over 24576 counts ---------------
__global__ void k_scan(const int* __restrict__ counts, int* __restrict__ offs,
                       int* __restrict__ cursor) {
    __shared__ int lds[257];
    int t = threadIdx.x;
    const int CH = NSEG / 256;  // 96
    int base = t * CH;
    int s = 0;
    for (int i = 0; i < CH; i++) s += counts[base + i];
    lds[t] = s;
    __syncthreads();
    if (t == 0) {
        int run = 0;
        for (int i = 0; i < 256; i++) { int v = lds[i]; lds[i] = run; run += v; }
        lds[256] = run;
    }
    __syncthreads();
    int run = lds[t];
    for (int i = 0; i < CH; i++) {
        int c = counts[base + i];
        offs[base + i] = run; cursor[base + i] = run;
        run += c;
    }
    if (t == 0) offs[NSEG] = lds[256];
}

// ---------------- kernel 4: scatter edge ids into CSR ----------------------
__global__ void k_scatter(const int* __restrict__ dst, int* __restrict__ cursor,
                          int* __restrict__ elist) {
    int id = blockIdx.x * blockDim.x + threadIdx.x;
    if (id >= NP * NE) return;
    int p = id / NE, e = id % NE;
    int pos = atomicAdd(&cursor[p * NT + dst[id]], 1);
    elist[pos] = e;
}

// ---------------- kernel 5: edge aggregation (1 wave per segment) ----------
__global__ __launch_bounds__(64) void k_agg(
        const float* __restrict__ feat, const int* __restrict__ indices,
        const float* __restrict__ attn, const float* __restrict__ ws_f,
        const int* __restrict__ offs, const int* __restrict__ elist,
        float* __restrict__ outs) {
    int b = blockIdx.x;
    int p = b / NT;
    int d = threadIdx.x;
    int j = d >> 1;
    bool isim = (d & 1) != 0;

    const float* fr = ws_f + FINALR_W + p * NL * ND2 * 2;
    float cr[NL], ci[NL];
#pragma unroll
    for (int l = 0; l < NL; l++) {
        cr[l] = fr[(l * ND2 + j) * 2 + 0];
        ci[l] = fr[(l * ND2 + j) * 2 + 1];
    }
    float at[NH];
#pragma unroll
    for (int h = 0; h < NH; h++) at[h] = attn[(p * NH + h) * IND + d];

    float ft[NH], se[NH];
#pragma unroll
    for (int h = 0; h < NH; h++) { ft[h] = 0.f; se[h] = 0.f; }

    int beg = offs[b], end = offs[b + 1];
    const int* idxp = indices + (long)p * NE * NL;

    for (int i = beg; i < end; i++) {
        int e = elist[i];
        int n0 = idxp[e * 3 + 0], n1 = idxp[e * 3 + 1], n2 = idxp[e * 3 + 2];
        int nn[3] = { n0, n1, n2 };
        float hid = 0.f;
#pragma unroll
        for (int l = 0; l < NL; l++) {
            float x = feat[(long)nn[l] * IND + d];
            float xp = __shfl_xor(x, 1);
            float re = isim ? xp : x;
            float im = isim ? x : xp;
            hid += isim ? (re * ci[l] + im * cr[l]) : (re * cr[l] - im * ci[l]);
        }
        hid *= (1.f / 3.f);
#pragma unroll
        for (int h = 0; h < NH; h++) {
            float v = hid * at[h];
#pragma unroll
            for (int off = 32; off; off >>= 1) v += __shfl_xor(v, off);
            float a = v > 0.f ? v : LALPHA * v;
            float eh = __expf(a);
            se[h] += eh;
            ft[h] += eh * hid;
        }
    }

    float* orow = outs + (long)b * NHD;
    bool has = end > beg;
#pragma unroll
    for (int h = 0; h < NH; h++) {
        float v = has ? ft[h] / fmaxf(se[h], 1e-20f) : 0.f;
        v = v > 0.f ? v : (__expf(v) - 1.f);   // elu
        orow[h * IND + d] = v;
    }
}

// ---------------- kernel 6: fc1 -> tanh -> sum over nodes ------------------
__global__ __launch_bounds__(128) void k_fc1(
        const float* __restrict__ outs, const float* __restrict__ fc1_w,
        const float* __restrict__ fc1_b, float* __restrict__ betaacc) {
    __shared__ float v[16 * NHD];  // 32 KB
    int bx = blockIdx.x;
    int p = bx / (NT / 16);
    int n0 = (bx % (NT / 16)) * 16;
    int t = threadIdx.x;
    const float* src = outs + (long)(p * NT + n0) * NHD;
    for (int i = t; i < 16 * NHD; i += 128) v[i] = src[i];
    __syncthreads();
    float acc[16];
#pragma unroll
    for (int n = 0; n < 16; n++) acc[n] = 0.f;
    for (int k = 0; k < NHD; k++) {
        float w = fc1_w[t * NHD + k];
#pragma unroll
        for (int n = 0; n < 16; n++) acc[n] += w * v[n * NHD + k];  // LDS broadcast
    }
    float bb = fc1_b[t];
    float s = 0.f;
#pragma unroll
    for (int n = 0; n < 16; n++) s += tanhf(acc[n] + bb);
    atomicAdd(&betaacc[p * NAD + t], s);
}

// ---------------- kernel 7: beta = softmax(mean_fc1 @ fc2) -----------------
__global__ void k_beta(const float* __restrict__ betaacc,
                       const float* __restrict__ fc2_w, float* __restrict__ beta) {
    __shared__ float lds[NP][NAD];
    int t = threadIdx.x;  // 128
    for (int p = 0; p < NP; p++)
        lds[p][t] = betaacc[p * NAD + t] * (1.f / NT) * fc2_w[t];
    __syncthreads();
    if (t == 0) {
        float s[NP];
        for (int p = 0; p < NP; p++) {
            s[p] = 0.f;
            for (int a = 0; a < NAD; a++) s[p] += lds[p][a];
        }
        float m = fmaxf(s[0], fmaxf(s[1], s[2]));
        float e0 = expf(s[0] - m), e1 = expf(s[1] - m), e2 = expf(s[2] - m);
        float inv = 1.f / (e0 + e1 + e2);
        beta[0] = e0 * inv; beta[1] = e1 * inv; beta[2] = e2 * inv;
    }
}

// ---------------- kernel 8: h = sum_p beta_p*outs_p ; h_fc = h @ fc_w^T ----
__global__ __launch_bounds__(256) void k_final(
        const float* __restrict__ outs, const float* __restrict__ beta,
        const float* __restrict__ fc_w, const float* __restrict__ fc_b,
        void* __restrict__ outp, const int* __restrict__ flag) {
    __shared__ float h[NHD];
    __shared__ float part[256];
    int n = blockIdx.x;
    int t = threadIdx.x;
    int f = *flag;
    float b0 = beta[0], b1 = beta[1], b2 = beta[2];
    const float* o0 = outs + (long)n * NHD;
    for (int d = t; d < NHD; d += 256) {
        float v = b0 * o0[d] + b1 * o0[(long)NT * NHD + d] + b2 * o0[2L * NT * NHD + d];
        h[d] = v;
        long idx = (long)NT * NOD + (long)n * NHD + d;
        if (f) ((float*)outp)[idx] = v;
        else   ((__hip_bfloat16*)outp)[idx] = __float2bfloat16(v);
    }
    __syncthreads();
    int o = t & 63, q = t >> 6;
    float s = 0.f;
    for (int k = q * 128; k < (q + 1) * 128; k++) s += h[k] * fc_w[o * NHD + k];
    part[t] = s;
    __syncthreads();
    if (t < 64) {
        float v = part[t] + part[t + 64] + part[t + 128] + part[t + 192] + fc_b[t];
        long idx = (long)n * NOD + t;
        if (f) ((float*)outp)[idx] = v;
        else   ((__hip_bfloat16*)outp)[idx] = __float2bfloat16(v);
    }
}

extern "C" void kernel_launch(void* const* d_in, const int* in_sizes, int n_in,
                              void* d_out, int out_size, void* d_ws, size_t ws_size,
                              hipStream_t stream) {
    const int* indices = (const int*)d_in[1];
    const int* dst     = (const int*)d_in[2];

    float* ws  = (float*)d_ws;
    int*   wsi = (int*)d_ws;

    hipMemsetAsync((char*)d_ws + BETAACC_W * 4, 0, NP * NAD * 4, stream);
    hipMemsetAsync((char*)d_ws + COUNTS_W * 4, 0, NSEG * 4, stream);

    k_detect<<<1, 1, 0, stream>>>((const unsigned short*)d_in[0], wsi + FLAG_W);

    auto cvt = [&](const void* s, int off, int n) {
        k_cvt<<<(n + 255) / 256, 256, 0, stream>>>(s, ws + off, n, wsi + FLAG_W);
    };
    cvt(d_in[0], FEATF_W, NN * IND);
    cvt(d_in[3], RVECF_W, NP * ND2 * 2);
    cvt(d_in[4], ATTNF_W, NP * NH * IND);
    cvt(d_in[5], FC1W_W, NAD * NHD);
    cvt(d_in[6], FC1B_W, NAD);
    cvt(d_in[7], FC2W_W, NAD);
    cvt(d_in[8], FCW_W, NOD * NHD);
    cvt(d_in[9], FCB_W, NOD);

    k_finalr<<<1, 128, 0, stream>>>(ws + RVECF_W, ws);
    k_count<<<(NP * NE + 255) / 256, 256, 0, stream>>>(dst, wsi + COUNTS_W);
    k_scan<<<1, 256, 0, stream>>>(wsi + COUNTS_W, wsi + OFFS_W, wsi + CURSOR_W);
    k_scatter<<<(NP * NE + 255) / 256, 256, 0, stream>>>(dst, wsi + CURSOR_W, wsi + ELIST_W);
    k_agg<<<NSEG, 64, 0, stream>>>(ws + FEATF_W, indices, ws + ATTNF_W, ws,
                                   wsi + OFFS_W, wsi + ELIST_W, ws + OUTS_W);
    k_fc1<<<NP * (NT / 16), 128, 0, stream>>>(ws + OUTS_W, ws + FC1W_W, ws + FC1B_W,
                                              ws + BETAACC_W);
    k_beta<<<1, 128, 0, stream>>>(ws + BETAACC_W, ws + FC2W_W, ws + BETA_W);
    k_final<<<NT, 256, 0, stream>>>(ws + OUTS_W, ws + BETA_W, ws + FCW_W, ws + FCB_W,
                                    d_out, wsi + FLAG_W);
}

// Round 3
// 709.159 us; speedup vs baseline: 1.7989x; 1.7989x over previous
//
#include <hip/hip_runtime.h>
#include <hip/hip_bf16.h>

// Problem constants (from reference)
#define NP   3        // metapaths
#define NE   250000   // edges per metapath
#define NL   3        // metapath length
#define NT   8192     // targets
#define NN   100000   // nodes
#define IND  64       // in_dim
#define ND2  32       // in_dim/2 complex pairs
#define NH   8        // heads
#define NAD  128      // attn_vec_dim
#define NOD  64       // out_dim
#define NHD  512      // heads * in_dim
#define LALPHA 0.01f
#define NSEG (NP*NT)
#define NB   8        // nodes per block in k_final

// ws layout, in 4-byte words (total ~76 MB)
#define FLAG_W    0         // 1 int   : 1 = inputs are f32, 0 = inputs are bf16
#define FINALR_W  64        // 576 f32 : final_r [P][L][32][2]
#define BETAACC_W 1024      // 384 f32
#define BETA_W    1472      // 4 f32
#define COUNTS_W  2048      // 24576 int
#define OFFS_W    26624     // 24577 int
#define CURSOR_W  51264     // 24576 int
#define ELIST_W   75904     // 750000 int
#define FEATF_W   825920    // 6.4M f32 : features staged f32
#define ATTNF_W   7225920   // 1536 f32
#define FC1W_W    7227456   // 65536 f32 : fc1_w TRANSPOSED [NHD][NAD]
#define FC1B_W    7292992   // 128 f32
#define FC2W_W    7293120   // 128 f32
#define FCW_W     7293248   // 32768 f32 : fc_w TRANSPOSED [NHD][NOD]
#define FCB_W     7326016   // 64 f32
#define RVECF_W   7326080   // 192 f32
#define OUTS_W    7326272   // 12.58M f32 : elu(outs) [P][NT][512]

__device__ __forceinline__ float bf2f(unsigned short u) {
    union { unsigned int i; float f; } c; c.i = ((unsigned int)u) << 16; return c.f;
}

// ---------------- kernel 0a: detect input dtype ----------------------------
__global__ void k_detect(const unsigned short* __restrict__ raw, int* __restrict__ flag) {
    if (threadIdx.x != 0 || blockIdx.x != 0) return;
    int wild = 0;
    for (int i = 0; i < 512; i++) {
        unsigned short u = raw[i];
        int e = (u >> 7) & 0xFF;
        if (u != 0 && (e < 0x60 || e > 0x90)) wild++;
    }
    *flag = (wild > 64) ? 1 : 0;
}

// ---------------- kernel 0b: convert float tensor to f32 staging -----------
__global__ void k_cvt(const void* __restrict__ src, float* __restrict__ dst, int n,
                      const int* __restrict__ flag) {
    int i = blockIdx.x * blockDim.x + threadIdx.x;
    if (i >= n) return;
    if (*flag) dst[i] = ((const float*)src)[i];
    else       dst[i] = bf2f(((const unsigned short*)src)[i]);
}

// ---------------- kernel 0c: convert + transpose [R][C] -> [C][R] ----------
__global__ void k_cvt_tr(const void* __restrict__ src, float* __restrict__ dst,
                         int R, int C, const int* __restrict__ flag) {
    int i = blockIdx.x * blockDim.x + threadIdx.x;
    if (i >= R * C) return;
    int r = i / C, c = i % C;
    float v;
    if (*flag) v = ((const float*)src)[i];
    else       v = bf2f(((const unsigned short*)src)[i]);
    dst[c * R + r] = v;
}

// ---------------- kernel 1: final rotation vectors -------------------------
__global__ void k_finalr(const float* __restrict__ r_vec, float* __restrict__ ws) {
    int k = threadIdx.x;
    if (k >= NP * ND2) return;
    int p = k / ND2, j = k % ND2;
    float re = r_vec[(p * ND2 + j) * 2 + 0];
    float im = r_vec[(p * ND2 + j) * 2 + 1];
    float inv = rsqrtf(re * re + im * im);
    float nre = re * inv, nim = im * inv;
    float f2r = 1.f, f2i = 0.f;
    float f1r = nre, f1i = -nim;
    float f0r = f1r * nre - f1i * nim;
    float f0i = f1r * nim + f1i * nre;
    float* fr = ws + FINALR_W + p * NL * ND2 * 2;
    fr[(0 * ND2 + j) * 2 + 0] = f0r; fr[(0 * ND2 + j) * 2 + 1] = f0i;
    fr[(1 * ND2 + j) * 2 + 0] = f1r; fr[(1 * ND2 + j) * 2 + 1] = f1i;
    fr[(2 * ND2 + j) * 2 + 0] = f2r; fr[(2 * ND2 + j) * 2 + 1] = f2i;
}

// ---------------- kernel 2: per-segment edge counts ------------------------
__global__ void k_count(const int* __restrict__ dst, int* __restrict__ counts) {
    int id = blockIdx.x * blockDim.x + threadIdx.x;
    if (id >= NP * NE) return;
    int p = id / NE;
    atomicAdd(&counts[p * NT + dst[id]], 1);
}

// ---------------- kernel 3: exclusive scan over 24576 counts ---------------
__global__ void k_scan(const int* __restrict__ counts, int* __restrict__ offs,
                       int* __restrict__ cursor) {
    __shared__ int lds[257];
    int t = threadIdx.x;
    const int CH = NSEG / 256;  // 96
    int base = t * CH;
    int s = 0;
    for (int i = 0; i < CH; i++) s += counts[base + i];
    lds[t] = s;
    __syncthreads();
    if (t == 0) {
        int run = 0;
        for (int i = 0; i < 256; i++) { int v = lds[i]; lds[i] = run; run += v; }
        lds[256] = run;
    }
    __syncthreads();
    int run = lds[t];
    for (int i = 0; i < CH; i++) {
        int c = counts[base + i];
        offs[base + i] = run; cursor[base + i] = run;
        run += c;
    }
    if (t == 0) offs[NSEG] = lds[256];
}

// ---------------- kernel 4: scatter edge ids into CSR ----------------------
__global__ void k_scatter(const int* __restrict__ dst, int* __restrict__ cursor,
                          int* __restrict__ elist) {
    int id = blockIdx.x * blockDim.x + threadIdx.x;
    if (id >= NP * NE) return;
    int p = id / NE, e = id % NE;
    int pos = atomicAdd(&cursor[p * NT + dst[id]], 1);
    elist[pos] = e;
}

// ---------------- kernel 5: edge aggregation (1 wave per segment) ----------
__global__ __launch_bounds__(64) void k_agg(
        const float* __restrict__ feat, const int* __restrict__ indices,
        const float* __restrict__ attn, const float* __restrict__ ws_f,
        const int* __restrict__ offs, const int* __restrict__ elist,
        float* __restrict__ outs) {
    int b = blockIdx.x;
    int p = b / NT;
    int d = threadIdx.x;
    int j = d >> 1;
    bool isim = (d & 1) != 0;

    const float* fr = ws_f + FINALR_W + p * NL * ND2 * 2;
    float cr[NL], ci[NL];
#pragma unroll
    for (int l = 0; l < NL; l++) {
        cr[l] = fr[(l * ND2 + j) * 2 + 0];
        ci[l] = fr[(l * ND2 + j) * 2 + 1];
    }
    float at[NH];
#pragma unroll
    for (int h = 0; h < NH; h++) at[h] = attn[(p * NH + h) * IND + d];

    float ft[NH], se[NH];
#pragma unroll
    for (int h = 0; h < NH; h++) { ft[h] = 0.f; se[h] = 0.f; }

    int beg = offs[b], end = offs[b + 1];
    const int* idxp = indices + (long)p * NE * NL;

    for (int i = beg; i < end; i++) {
        int e = elist[i];
        int n0 = idxp[e * 3 + 0], n1 = idxp[e * 3 + 1], n2 = idxp[e * 3 + 2];
        int nn[3] = { n0, n1, n2 };
        float hid = 0.f;
#pragma unroll
        for (int l = 0; l < NL; l++) {
            float x = feat[(long)nn[l] * IND + d];
            float xp = __shfl_xor(x, 1);
            float re = isim ? xp : x;
            float im = isim ? x : xp;
            hid += isim ? (re * ci[l] + im * cr[l]) : (re * cr[l] - im * ci[l]);
        }
        hid *= (1.f / 3.f);
#pragma unroll
        for (int h = 0; h < NH; h++) {
            float v = hid * at[h];
#pragma unroll
            for (int off = 32; off; off >>= 1) v += __shfl_xor(v, off);
            float a = v > 0.f ? v : LALPHA * v;
            float eh = __expf(a);
            se[h] += eh;
            ft[h] += eh * hid;
        }
    }

    float* orow = outs + (long)b * NHD;
    bool has = end > beg;
#pragma unroll
    for (int h = 0; h < NH; h++) {
        float v = has ? ft[h] / fmaxf(se[h], 1e-20f) : 0.f;
        v = v > 0.f ? v : (__expf(v) - 1.f);   // elu
        orow[h * IND + d] = v;
    }
}

// ---------------- kernel 6: fc1 -> tanh -> sum over nodes ------------------
// fc1_wT is [NHD][NAD]: lane t reads fc1_wT[k*NAD+t] -> coalesced
__global__ __launch_bounds__(128) void k_fc1(
        const float* __restrict__ outs, const float* __restrict__ fc1_wT,
        const float* __restrict__ fc1_b, float* __restrict__ betaacc) {
    __shared__ float v[16 * NHD];  // 32 KB
    int bx = blockIdx.x;
    int p = bx / (NT / 16);
    int n0 = (bx % (NT / 16)) * 16;
    int t = threadIdx.x;
    const float* src = outs + (long)(p * NT + n0) * NHD;
    for (int i = t; i < 16 * NHD; i += 128) v[i] = src[i];
    __syncthreads();
    float acc[16];
#pragma unroll
    for (int n = 0; n < 16; n++) acc[n] = 0.f;
    for (int k = 0; k < NHD; k++) {
        float w = fc1_wT[k * NAD + t];
#pragma unroll
        for (int n = 0; n < 16; n++) acc[n] += w * v[n * NHD + k];  // LDS broadcast
    }
    float bb = fc1_b[t];
    float s = 0.f;
#pragma unroll
    for (int n = 0; n < 16; n++) s += tanhf(acc[n] + bb);
    atomicAdd(&betaacc[p * NAD + t], s);
}

// ---------------- kernel 7: beta = softmax(mean_fc1 @ fc2) -----------------
__global__ void k_beta(const float* __restrict__ betaacc,
                       const float* __restrict__ fc2_w, float* __restrict__ beta) {
    __shared__ float lds[NP][NAD];
    int t = threadIdx.x;  // 128
    for (int p = 0; p < NP; p++)
        lds[p][t] = betaacc[p * NAD + t] * (1.f / NT) * fc2_w[t];
    __syncthreads();
    if (t == 0) {
        float s[NP];
        for (int p = 0; p < NP; p++) {
            s[p] = 0.f;
            for (int a = 0; a < NAD; a++) s[p] += lds[p][a];
        }
        float m = fmaxf(s[0], fmaxf(s[1], s[2]));
        float e0 = expf(s[0] - m), e1 = expf(s[1] - m), e2 = expf(s[2] - m);
        float inv = 1.f / (e0 + e1 + e2);
        beta[0] = e0 * inv; beta[1] = e1 * inv; beta[2] = e2 * inv;
    }
}

// ---------------- kernel 8: h = sum_p beta_p*outs_p ; h_fc = h @ fc_wT -----
// NB=8 nodes per block; fc_wT [NHD][NOD]: lane l reads fc_wT[k*64+l] -> coalesced.
__global__ __launch_bounds__(256) void k_final(
        const float* __restrict__ outs, const float* __restrict__ beta,
        const float* __restrict__ fc_wT, const float* __restrict__ fc_b,
        void* __restrict__ outp, const int* __restrict__ flag) {
    __shared__ float h[NB * NHD];     // 16 KB
    __shared__ float part[4 * NB * NOD];  // 8 KB
    int n0 = blockIdx.x * NB;
    int t = threadIdx.x;
    int f = *flag;
    float b0 = beta[0], b1 = beta[1], b2 = beta[2];
    const float* o0 = outs + (long)n0 * NHD;
    // phase 1: beta-combine into LDS + write h output (coalesced)
    for (int i = t; i < NB * NHD; i += 256) {
        float v = b0 * o0[i] + b1 * o0[(long)NT * NHD + i] + b2 * o0[2L * NT * NHD + i];
        h[i] = v;
        long idx = (long)NT * NOD + (long)n0 * NHD + i;
        if (f) ((float*)outp)[idx] = v;
        else   ((__hip_bfloat16*)outp)[idx] = __float2bfloat16(v);
    }
    __syncthreads();
    // phase 2: GEMV. wave w handles k in [w*128,(w+1)*128), lane l -> out dim l
    int w = t >> 6, l = t & 63;
    float acc[NB];
#pragma unroll
    for (int n = 0; n < NB; n++) acc[n] = 0.f;
    for (int k = w * 128; k < (w + 1) * 128; k++) {
        float wv = fc_wT[k * NOD + l];
#pragma unroll
        for (int n = 0; n < NB; n++) acc[n] += h[n * NHD + k] * wv;
    }
#pragma unroll
    for (int n = 0; n < NB; n++) part[(w * NB + n) * NOD + l] = acc[n];
    __syncthreads();
    // phase 3: reduce 4 wave-partials, add bias, store (2 outputs per thread)
    for (int idx = t; idx < NB * NOD; idx += 256) {
        int n = idx >> 6, ll = idx & 63;
        float v = part[(0 * NB + n) * NOD + ll] + part[(1 * NB + n) * NOD + ll]
                + part[(2 * NB + n) * NOD + ll] + part[(3 * NB + n) * NOD + ll]
                + fc_b[ll];
        long oidx = (long)(n0 + n) * NOD + ll;
        if (f) ((float*)outp)[oidx] = v;
        else   ((__hip_bfloat16*)outp)[oidx] = __float2bfloat16(v);
    }
}

extern "C" void kernel_launch(void* const* d_in, const int* in_sizes, int n_in,
                              void* d_out, int out_size, void* d_ws, size_t ws_size,
                              hipStream_t stream) {
    const int* indices = (const int*)d_in[1];
    const int* dst     = (const int*)d_in[2];

    float* ws  = (float*)d_ws;
    int*   wsi = (int*)d_ws;

    hipMemsetAsync((char*)d_ws + BETAACC_W * 4, 0, NP * NAD * 4, stream);
    hipMemsetAsync((char*)d_ws + COUNTS_W * 4, 0, NSEG * 4, stream);

    k_detect<<<1, 1, 0, stream>>>((const unsigned short*)d_in[0], wsi + FLAG_W);

    auto cvt = [&](const void* s, int off, int n) {
        k_cvt<<<(n + 255) / 256, 256, 0, stream>>>(s, ws + off, n, wsi + FLAG_W);
    };
    cvt(d_in[0], FEATF_W, NN * IND);
    cvt(d_in[3], RVECF_W, NP * ND2 * 2);
    cvt(d_in[4], ATTNF_W, NP * NH * IND);
    k_cvt_tr<<<(NAD * NHD + 255) / 256, 256, 0, stream>>>(d_in[5], ws + FC1W_W,
                                                          NAD, NHD, wsi + FLAG_W);
    cvt(d_in[6], FC1B_W, NAD);
    cvt(d_in[7], FC2W_W, NAD);
    k_cvt_tr<<<(NOD * NHD + 255) / 256, 256, 0, stream>>>(d_in[8], ws + FCW_W,
                                                          NOD, NHD, wsi + FLAG_W);
    cvt(d_in[9], FCB_W, NOD);

    k_finalr<<<1, 128, 0, stream>>>(ws + RVECF_W, ws);
    k_count<<<(NP * NE + 255) / 256, 256, 0, stream>>>(dst, wsi + COUNTS_W);
    k_scan<<<1, 256, 0, stream>>>(wsi + COUNTS_W, wsi + OFFS_W, wsi + CURSOR_W);
    k_scatter<<<(NP * NE + 255) / 256, 256, 0, stream>>>(dst, wsi + CURSOR_W, wsi + ELIST_W);
    k_agg<<<NSEG, 64, 0, stream>>>(ws + FEATF_W, indices, ws + ATTNF_W, ws,
                                   wsi + OFFS_W, wsi + ELIST_W, ws + OUTS_W);
    k_fc1<<<NP * (NT / 16), 128, 0, stream>>>(ws + OUTS_W, ws + FC1W_W, ws + FC1B_W,
                                              ws + BETAACC_W);
    k_beta<<<1, 128, 0, stream>>>(ws + BETAACC_W, ws + FC2W_W, ws + BETA_W);
    k_final<<<NT / NB, 256, 0, stream>>>(ws + OUTS_W, ws + BETA_W, ws + FCW_W, ws + FCB_W,
                                         d_out, wsi + FLAG_W);
}

// Round 4
// 492.330 us; speedup vs baseline: 2.5911x; 1.4404x over previous
//
#include <hip/hip_runtime.h>
#include <hip/hip_bf16.h>

// Problem constants (from reference)
#define NP   3        // metapaths
#define NE   250000   // edges per metapath
#define NL   3        // metapath length
#define NT   8192     // targets
#define NN   100000   // nodes
#define IND  64       // in_dim
#define ND2  32       // in_dim/2 complex pairs
#define NH   8        // heads
#define NAD  128      // attn_vec_dim
#define NOD  64       // out_dim
#define NHD  512      // heads * in_dim
#define LALPHA 0.01f
#define NSEG (NP*NT)
#define NB   8        // nodes per block in k_final

// ---------------- NEW-path ws layout (words). NEED = 29363456 words ---------
#define FLAG_W    0
#define FINALR_W  64        // 576
#define ATILDE_W  704       // 4608 : atilde [p][l][h][64] (1/3 folded in)
#define BETAACC_N 5376      // 384
#define BETA_N    5760      // 4
#define COUNTS_N  6144      // 24576
#define OFFS_N    30720     // 24577
#define CURSOR_N  55360     // 24576
#define EIDX_N    80000     // 3000000 (750000 int4)
#define ATTNF_N   3080000   // 1536
#define FC1W_N    3081600   // 65536 (transposed [NHD][NAD])
#define FC1B_N    3147136   // 128
#define FC2W_N    3147264   // 128
#define FCW_N     3147392   // 32768 (transposed [NHD][NOD])
#define FCB_N     3180160   // 64
#define RVEC_N    3180224   // 192
#define FEATF_N   3180544   // 6400000
#define SCORE_N   9580544   // 7200000 : S [9][NN][8]
#define OUTS_N    16780544  // 12582912
#define NEED_WORDS 29363456UL

// ---------------- FALLBACK ws layout (round-3 proven, ~79.6 MB) -------------
#define BETAACC_F 1024
#define BETA_F    1472
#define COUNTS_F  2048
#define OFFS_F    26624
#define CURSOR_F  51264
#define ELIST_F   75904
#define FEATF_F   825920
#define ATTNF_F   7225920
#define FC1W_F    7227456
#define FC1B_F    7292992
#define FC2W_F    7293120
#define FCW_F     7293248
#define FCB_F     7326016
#define RVEC_F    7326080
#define OUTS_F    7326272

__device__ __forceinline__ float bf2f(unsigned short u) {
    union { unsigned int i; float f; } c; c.i = ((unsigned int)u) << 16; return c.f;
}

// ---------------- dtype detect ---------------------------------------------
__global__ void k_detect(const unsigned short* __restrict__ raw, int* __restrict__ flag) {
    if (threadIdx.x != 0 || blockIdx.x != 0) return;
    int wild = 0;
    for (int i = 0; i < 512; i++) {
        unsigned short u = raw[i];
        int e = (u >> 7) & 0xFF;
        if (u != 0 && (e < 0x60 || e > 0x90)) wild++;
    }
    *flag = (wild > 64) ? 1 : 0;
}

__global__ void k_cvt(const void* __restrict__ src, float* __restrict__ dst, int n,
                      const int* __restrict__ flag) {
    int i = blockIdx.x * blockDim.x + threadIdx.x;
    if (i >= n) return;
    if (*flag) dst[i] = ((const float*)src)[i];
    else       dst[i] = bf2f(((const unsigned short*)src)[i]);
}

__global__ void k_cvt_tr(const void* __restrict__ src, float* __restrict__ dst,
                         int R, int C, const int* __restrict__ flag) {
    int i = blockIdx.x * blockDim.x + threadIdx.x;
    if (i >= R * C) return;
    int r = i / C, c = i % C;
    float v;
    if (*flag) v = ((const float*)src)[i];
    else       v = bf2f(((const unsigned short*)src)[i]);
    dst[c * R + r] = v;
}

// ---------------- final rotation vectors -----------------------------------
__global__ void k_finalr(const float* __restrict__ r_vec, float* __restrict__ ws) {
    int k = threadIdx.x;
    if (k >= NP * ND2) return;
    int p = k / ND2, j = k % ND2;
    float re = r_vec[(p * ND2 + j) * 2 + 0];
    float im = r_vec[(p * ND2 + j) * 2 + 1];
    float inv = rsqrtf(re * re + im * im);
    float nre = re * inv, nim = im * inv;
    float f1r = nre, f1i = -nim;                  // f[1] = conj(r)
    float f0r = f1r * nre - f1i * nim;            // f[0] = f[1]*r
    float f0i = f1r * nim + f1i * nre;
    float* fr = ws + FINALR_W + p * NL * ND2 * 2;
    fr[(0 * ND2 + j) * 2 + 0] = f0r; fr[(0 * ND2 + j) * 2 + 1] = f0i;
    fr[(1 * ND2 + j) * 2 + 0] = f1r; fr[(1 * ND2 + j) * 2 + 1] = f1i;
    fr[(2 * ND2 + j) * 2 + 0] = 1.f; fr[(2 * ND2 + j) * 2 + 1] = 0.f;
}

// ---------------- atilde[p][l][h][d] = (1/3) * cmul(at[p,h], conj(c_pl))[d] -
__global__ void k_atilde(const float* __restrict__ finalr, const float* __restrict__ attnf,
                         float* __restrict__ atil) {
    int t = blockIdx.x * 256 + threadIdx.x;
    if (t >= NP * NL * NH * IND) return;
    int d = t & 63, h = (t >> 6) & 7, l = (t >> 9) % 3, p = t / (64 * 8 * 3);
    int j = d >> 1; bool im = (d & 1) != 0;
    float cr = finalr[(p * NL * ND2 + l * ND2 + j) * 2 + 0];
    float ci = finalr[(p * NL * ND2 + l * ND2 + j) * 2 + 1];
    float ar = attnf[(p * NH + h) * IND + 2 * j];
    float ai = attnf[(p * NH + h) * IND + 2 * j + 1];
    float v = im ? (ai * cr - ar * ci) : (ar * cr + ai * ci);
    atil[t] = v * (1.f / 3.f);
}

// ---------------- per-node scores S[c][n][h], c = p*3+l ---------------------
__global__ __launch_bounds__(256) void k_score(const float* __restrict__ feat,
                                               const float* __restrict__ atil,
                                               float* __restrict__ S) {
    __shared__ float xs[32][68];
    __shared__ float as[72][68];
    int t = threadIdx.x;
    int nbase = blockIdx.x * 32;
    for (int i = t; i < 72 * 64; i += 256) as[i >> 6][i & 63] = atil[i];
    for (int i = t; i < 32 * 64; i += 256)
        xs[i >> 6][i & 63] = feat[(long)(nbase + (i >> 6)) * IND + (i & 63)];
    __syncthreads();
    int w = t >> 6, lane = t & 63;
    int g = lane >> 3, h = lane & 7;
    int node = w * 8 + g;  // 0..31
    float acc[9];
#pragma unroll
    for (int c = 0; c < 9; c++) acc[c] = 0.f;
    for (int ch = 0; ch < 16; ch++) {
        float4 xv = *(const float4*)&xs[node][ch * 4];
#pragma unroll
        for (int c = 0; c < 9; c++) {
            float4 av = *(const float4*)&as[c * 8 + h][ch * 4];
            acc[c] += xv.x * av.x + xv.y * av.y + xv.z * av.z + xv.w * av.w;
        }
    }
#pragma unroll
    for (int c = 0; c < 9; c++)
        S[((long)c * NN + nbase + node) * 8 + h] = acc[c];
}

// ---------------- CSR build -------------------------------------------------
__global__ void k_count(const int* __restrict__ dst, int* __restrict__ counts) {
    int id = blockIdx.x * blockDim.x + threadIdx.x;
    if (id >= NP * NE) return;
    int p = id / NE;
    atomicAdd(&counts[p * NT + dst[id]], 1);
}

__global__ void k_scan(const int* __restrict__ counts, int* __restrict__ offs,
                       int* __restrict__ cursor) {
    __shared__ int lds[257];
    int t = threadIdx.x;
    const int CH = NSEG / 256;
    int base = t * CH;
    int s = 0;
    for (int i = 0; i < CH; i++) s += counts[base + i];
    lds[t] = s;
    __syncthreads();
    if (t == 0) {
        int run = 0;
        for (int i = 0; i < 256; i++) { int v = lds[i]; lds[i] = run; run += v; }
        lds[256] = run;
    }
    __syncthreads();
    int run = lds[t];
    for (int i = 0; i < CH; i++) {
        int c = counts[base + i];
        offs[base + i] = run; cursor[base + i] = run;
        run += c;
    }
    if (t == 0) offs[NSEG] = lds[256];
}

// new: scatter expanded node triples
__global__ void k_scatter2(const int* __restrict__ dst, const int* __restrict__ indices,
                           int* __restrict__ cursor, int4* __restrict__ eidx) {
    int id = blockIdx.x * blockDim.x + threadIdx.x;
    if (id >= NP * NE) return;
    int p = id / NE, e = id % NE;
    int pos = atomicAdd(&cursor[p * NT + dst[id]], 1);
    const int* ip = indices + (long)p * NE * NL + (long)e * NL;
    eidx[pos] = make_int4(ip[0], ip[1], ip[2], 0);
}

// fallback: scatter edge id only
__global__ void k_scatter(const int* __restrict__ dst, int* __restrict__ cursor,
                          int* __restrict__ elist) {
    int id = blockIdx.x * blockDim.x + threadIdx.x;
    if (id >= NP * NE) return;
    int p = id / NE, e = id % NE;
    int pos = atomicAdd(&cursor[p * NT + dst[id]], 1);
    elist[pos] = e;
}

// ---------------- NEW edge aggregation: no shuffles, no LDS -----------------
// lane = 8*h + q handles (head h, dims d in [8q, 8q+8))
__global__ __launch_bounds__(64) void k_agg2(
        const float* __restrict__ feat, const int4* __restrict__ eidx,
        const float* __restrict__ S, const float* __restrict__ finalr,
        const int* __restrict__ offs, float* __restrict__ outs) {
    int b = blockIdx.x;
    int p = b / NT;
    int t = threadIdx.x;
    int h = t >> 3, q = t & 7;

    float a0[8], a1[8], a2[8];
#pragma unroll
    for (int r = 0; r < 8; r++) { a0[r] = 0.f; a1[r] = 0.f; a2[r] = 0.f; }
    float se = 0.f;

    int beg = offs[b], end = offs[b + 1];
    const float* S0 = S + ((long)(p * 3 + 0) * NN) * 8 + h;
    const float* S1 = S + ((long)(p * 3 + 1) * NN) * 8 + h;
    const float* S2 = S + ((long)(p * 3 + 2) * NN) * 8 + h;

#pragma unroll 2
    for (int i = beg; i < end; i++) {
        int4 e = eidx[i];
        float s = S0[(long)e.x * 8] + S1[(long)e.y * 8] + S2[(long)e.z * 8];
        float a = s > 0.f ? s : LALPHA * s;
        float eh = __expf(a);
        se += eh;
        const float4* r0 = (const float4*)(feat + ((long)e.x << 6) + (q << 3));
        const float4* r1 = (const float4*)(feat + ((long)e.y << 6) + (q << 3));
        const float4* r2 = (const float4*)(feat + ((long)e.z << 6) + (q << 3));
        float4 x0a = r0[0], x0b = r0[1];
        float4 x1a = r1[0], x1b = r1[1];
        float4 x2a = r2[0], x2b = r2[1];
        a0[0] += eh * x0a.x; a0[1] += eh * x0a.y; a0[2] += eh * x0a.z; a0[3] += eh * x0a.w;
        a0[4] += eh * x0b.x; a0[5] += eh * x0b.y; a0[6] += eh * x0b.z; a0[7] += eh * x0b.w;
        a1[0] += eh * x1a.x; a1[1] += eh * x1a.y; a1[2] += eh * x1a.z; a1[3] += eh * x1a.w;
        a1[4] += eh * x1b.x; a1[5] += eh * x1b.y; a1[6] += eh * x1b.z; a1[7] += eh * x1b.w;
        a2[0] += eh * x2a.x; a2[1] += eh * x2a.y; a2[2] += eh * x2a.z; a2[3] += eh * x2a.w;
        a2[4] += eh * x2b.x; a2[5] += eh * x2b.y; a2[6] += eh * x2b.z; a2[7] += eh * x2b.w;
    }

    // epilogue: ft = (1/3) * sum_l rot_l(acc_l) / se ; elu ; store
    const float* fr = finalr + p * NL * ND2 * 2;
    float sc = (end > beg) ? (1.f / 3.f) / se : 0.f;
    float o8[8];
#pragma unroll
    for (int jj = 0; jj < 4; jj++) {
        int j = 4 * q + jj;
        float c0r = fr[(0 * ND2 + j) * 2 + 0], c0i = fr[(0 * ND2 + j) * 2 + 1];
        float c1r = fr[(1 * ND2 + j) * 2 + 0], c1i = fr[(1 * ND2 + j) * 2 + 1];
        float ar, ai, vr, vi;
        ar = a0[2 * jj]; ai = a0[2 * jj + 1];
        vr = ar * c0r - ai * c0i; vi = ar * c0i + ai * c0r;
        ar = a1[2 * jj]; ai = a1[2 * jj + 1];
        vr += ar * c1r - ai * c1i; vi += ar * c1i + ai * c1r;
        vr += a2[2 * jj]; vi += a2[2 * jj + 1];   // l=2 rotation is identity
        vr *= sc; vi *= sc;
        o8[2 * jj]     = vr > 0.f ? vr : __expf(vr) - 1.f;
        o8[2 * jj + 1] = vi > 0.f ? vi : __expf(vi) - 1.f;
    }
    float* orow = outs + (long)b * NHD + (h << 6) + (q << 3);
    *(float4*)orow       = make_float4(o8[0], o8[1], o8[2], o8[3]);
    *(float4*)(orow + 4) = make_float4(o8[4], o8[5], o8[6], o8[7]);
}

// ---------------- FALLBACK edge aggregation (round-3 proven) ----------------
__global__ __launch_bounds__(64) void k_agg(
        const float* __restrict__ feat, const int* __restrict__ indices,
        const float* __restrict__ attn, const float* __restrict__ ws_f,
        const int* __restrict__ offs, const int* __restrict__ elist,
        float* __restrict__ outs) {
    int b = blockIdx.x;
    int p = b / NT;
    int d = threadIdx.x;
    int j = d >> 1;
    bool isim = (d & 1) != 0;
    const float* fr = ws_f + FINALR_W + p * NL * ND2 * 2;
    float cr[NL], ci[NL];
#pragma unroll
    for (int l = 0; l < NL; l++) {
        cr[l] = fr[(l * ND2 + j) * 2 + 0];
        ci[l] = fr[(l * ND2 + j) * 2 + 1];
    }
    float at[NH];
#pragma unroll
    for (int h = 0; h < NH; h++) at[h] = attn[(p * NH + h) * IND + d];
    float ft[NH], se[NH];
#pragma unroll
    for (int h = 0; h < NH; h++) { ft[h] = 0.f; se[h] = 0.f; }
    int beg = offs[b], end = offs[b + 1];
    const int* idxp = indices + (long)p * NE * NL;
    for (int i = beg; i < end; i++) {
        int e = elist[i];
        int nn[3] = { idxp[e * 3 + 0], idxp[e * 3 + 1], idxp[e * 3 + 2] };
        float hid = 0.f;
#pragma unroll
        for (int l = 0; l < NL; l++) {
            float x = feat[(long)nn[l] * IND + d];
            float xp = __shfl_xor(x, 1);
            float re = isim ? xp : x;
            float im = isim ? x : xp;
            hid += isim ? (re * ci[l] + im * cr[l]) : (re * cr[l] - im * ci[l]);
        }
        hid *= (1.f / 3.f);
#pragma unroll
        for (int h = 0; h < NH; h++) {
            float v = hid * at[h];
#pragma unroll
            for (int off = 32; off; off >>= 1) v += __shfl_xor(v, off);
            float a = v > 0.f ? v : LALPHA * v;
            float eh = __expf(a);
            se[h] += eh;
            ft[h] += eh * hid;
        }
    }
    float* orow = outs + (long)b * NHD;
    bool has = end > beg;
#pragma unroll
    for (int h = 0; h < NH; h++) {
        float v = has ? ft[h] / fmaxf(se[h], 1e-20f) : 0.f;
        v = v > 0.f ? v : (__expf(v) - 1.f);
        orow[h * IND + d] = v;
    }
}

// ---------------- fc1 -> tanh -> sum over nodes -----------------------------
__global__ __launch_bounds__(128) void k_fc1(
        const float* __restrict__ outs, const float* __restrict__ fc1_wT,
        const float* __restrict__ fc1_b, float* __restrict__ betaacc) {
    __shared__ float v[16 * NHD];
    int bx = blockIdx.x;
    int p = bx / (NT / 16);
    int n0 = (bx % (NT / 16)) * 16;
    int t = threadIdx.x;
    const float* src = outs + (long)(p * NT + n0) * NHD;
    for (int i = t; i < 16 * NHD; i += 128) v[i] = src[i];
    __syncthreads();
    float acc[16];
#pragma unroll
    for (int n = 0; n < 16; n++) acc[n] = 0.f;
    for (int k = 0; k < NHD; k++) {
        float w = fc1_wT[k * NAD + t];
#pragma unroll
        for (int n = 0; n < 16; n++) acc[n] += w * v[n * NHD + k];
    }
    float bb = fc1_b[t];
    float s = 0.f;
#pragma unroll
    for (int n = 0; n < 16; n++) s += tanhf(acc[n] + bb);
    atomicAdd(&betaacc[p * NAD + t], s);
}

__global__ void k_beta(const float* __restrict__ betaacc,
                       const float* __restrict__ fc2_w, float* __restrict__ beta) {
    __shared__ float lds[NP][NAD];
    int t = threadIdx.x;
    for (int p = 0; p < NP; p++)
        lds[p][t] = betaacc[p * NAD + t] * (1.f / NT) * fc2_w[t];
    __syncthreads();
    if (t == 0) {
        float s[NP];
        for (int p = 0; p < NP; p++) {
            s[p] = 0.f;
            for (int a = 0; a < NAD; a++) s[p] += lds[p][a];
        }
        float m = fmaxf(s[0], fmaxf(s[1], s[2]));
        float e0 = expf(s[0] - m), e1 = expf(s[1] - m), e2 = expf(s[2] - m);
        float inv = 1.f / (e0 + e1 + e2);
        beta[0] = e0 * inv; beta[1] = e1 * inv; beta[2] = e2 * inv;
    }
}

__global__ __launch_bounds__(256) void k_final(
        const float* __restrict__ outs, const float* __restrict__ beta,
        const float* __restrict__ fc_wT, const float* __restrict__ fc_b,
        void* __restrict__ outp, const int* __restrict__ flag) {
    __shared__ float h[NB * NHD];
    __shared__ float part[4 * NB * NOD];
    int n0 = blockIdx.x * NB;
    int t = threadIdx.x;
    int f = *flag;
    float b0 = beta[0], b1 = beta[1], b2 = beta[2];
    const float* o0 = outs + (long)n0 * NHD;
    for (int i = t; i < NB * NHD; i += 256) {
        float v = b0 * o0[i] + b1 * o0[(long)NT * NHD + i] + b2 * o0[2L * NT * NHD + i];
        h[i] = v;
        long idx = (long)NT * NOD + (long)n0 * NHD + i;
        if (f) ((float*)outp)[idx] = v;
        else   ((__hip_bfloat16*)outp)[idx] = __float2bfloat16(v);
    }
    __syncthreads();
    int w = t >> 6, l = t & 63;
    float acc[NB];
#pragma unroll
    for (int n = 0; n < NB; n++) acc[n] = 0.f;
    for (int k = w * 128; k < (w + 1) * 128; k++) {
        float wv = fc_wT[k * NOD + l];
#pragma unroll
        for (int n = 0; n < NB; n++) acc[n] += h[n * NHD + k] * wv;
    }
#pragma unroll
    for (int n = 0; n < NB; n++) part[(w * NB + n) * NOD + l] = acc[n];
    __syncthreads();
    for (int idx = t; idx < NB * NOD; idx += 256) {
        int n = idx >> 6, ll = idx & 63;
        float v = part[(0 * NB + n) * NOD + ll] + part[(1 * NB + n) * NOD + ll]
                + part[(2 * NB + n) * NOD + ll] + part[(3 * NB + n) * NOD + ll]
                + fc_b[ll];
        long oidx = (long)(n0 + n) * NOD + ll;
        if (f) ((float*)outp)[oidx] = v;
        else   ((__hip_bfloat16*)outp)[oidx] = __float2bfloat16(v);
    }
}

extern "C" void kernel_launch(void* const* d_in, const int* in_sizes, int n_in,
                              void* d_out, int out_size, void* d_ws, size_t ws_size,
                              hipStream_t stream) {
    const int* indices = (const int*)d_in[1];
    const int* dst     = (const int*)d_in[2];

    float* ws  = (float*)d_ws;
    int*   wsi = (int*)d_ws;

    bool big = ws_size >= NEED_WORDS * 4UL;

    // layout-dependent offsets
    const int betaacc = big ? BETAACC_N : BETAACC_F;
    const int beta    = big ? BETA_N    : BETA_F;
    const int counts  = big ? COUNTS_N  : COUNTS_F;
    const int offs    = big ? OFFS_N    : OFFS_F;
    const int cursor  = big ? CURSOR_N  : CURSOR_F;
    const int featf   = big ? FEATF_N   : FEATF_F;
    const int attnf   = big ? ATTNF_N   : ATTNF_F;
    const int fc1w    = big ? FC1W_N    : FC1W_F;
    const int fc1b    = big ? FC1B_N    : FC1B_F;
    const int fc2w    = big ? FC2W_N    : FC2W_F;
    const int fcw     = big ? FCW_N     : FCW_F;
    const int fcb     = big ? FCB_N     : FCB_F;
    const int rvec    = big ? RVEC_N    : RVEC_F;
    const int outsw   = big ? OUTS_N    : OUTS_F;

    hipMemsetAsync((char*)d_ws + (size_t)betaacc * 4, 0, NP * NAD * 4, stream);
    hipMemsetAsync((char*)d_ws + (size_t)counts * 4, 0, NSEG * 4, stream);

    k_detect<<<1, 1, 0, stream>>>((const unsigned short*)d_in[0], wsi + FLAG_W);

    auto cvt = [&](const void* s, int off, int n) {
        k_cvt<<<(n + 255) / 256, 256, 0, stream>>>(s, ws + off, n, wsi + FLAG_W);
    };
    cvt(d_in[0], featf, NN * IND);
    cvt(d_in[3], rvec, NP * ND2 * 2);
    cvt(d_in[4], attnf, NP * NH * IND);
    k_cvt_tr<<<(NAD * NHD + 255) / 256, 256, 0, stream>>>(d_in[5], ws + fc1w,
                                                          NAD, NHD, wsi + FLAG_W);
    cvt(d_in[6], fc1b, NAD);
    cvt(d_in[7], fc2w, NAD);
    k_cvt_tr<<<(NOD * NHD + 255) / 256, 256, 0, stream>>>(d_in[8], ws + fcw,
                                                          NOD, NHD, wsi + FLAG_W);
    cvt(d_in[9], fcb, NOD);

    k_finalr<<<1, 128, 0, stream>>>(ws + rvec, ws);
    k_count<<<(NP * NE + 255) / 256, 256, 0, stream>>>(dst, wsi + counts);
    k_scan<<<1, 256, 0, stream>>>(wsi + counts, wsi + offs, wsi + cursor);

    if (big) {
        k_atilde<<<18, 256, 0, stream>>>(ws + FINALR_W, ws + attnf, ws + ATILDE_W);
        k_score<<<NN / 32, 256, 0, stream>>>(ws + featf, ws + ATILDE_W, ws + SCORE_N);
        k_scatter2<<<(NP * NE + 255) / 256, 256, 0, stream>>>(dst, indices,
                                                              wsi + cursor,
                                                              (int4*)(wsi + EIDX_N));
        k_agg2<<<NSEG, 64, 0, stream>>>(ws + featf, (const int4*)(wsi + EIDX_N),
                                        ws + SCORE_N, ws + FINALR_W,
                                        wsi + offs, ws + outsw);
    } else {
        k_scatter<<<(NP * NE + 255) / 256, 256, 0, stream>>>(dst, wsi + cursor,
                                                             wsi + ELIST_F);
        k_agg<<<NSEG, 64, 0, stream>>>(ws + featf, indices, ws + attnf, ws,
                                       wsi + offs, wsi + ELIST_F, ws + outsw);
    }

    k_fc1<<<NP * (NT / 16), 128, 0, stream>>>(ws + outsw, ws + fc1w, ws + fc1b,
                                              ws + betaacc);
    k_beta<<<1, 128, 0, stream>>>(ws + betaacc, ws + fc2w, ws + beta);
    k_final<<<NT / NB, 256, 0, stream>>>(ws + outsw, ws + beta, ws + fcw, ws + fcb,
                                         d_out, wsi + FLAG_W);
}

// Round 5
// 454.336 us; speedup vs baseline: 2.8078x; 1.0836x over previous
//
#include <hip/hip_runtime.h>
#include <hip/hip_bf16.h>
#include <hip/hip_fp16.h>

// Problem constants (from reference)
#define NP   3        // metapaths
#define NE   250000   // edges per metapath
#define NL   3        // metapath length
#define NT   8192     // targets
#define NN   100000   // nodes
#define IND  64       // in_dim
#define ND2  32       // in_dim/2 complex pairs
#define NH   8        // heads
#define NAD  128      // attn_vec_dim
#define NOD  64       // out_dim
#define NHD  512      // heads * in_dim
#define LALPHA 0.01f
#define NSEG (NP*NT)
#define NB   8        // nodes per block in k_final

typedef __attribute__((ext_vector_type(8))) _Float16 half8;

// ---------------- NEW-path ws layout (words). NEED = 26163456 words ---------
#define FLAG_W    0
#define FINALR_W  64        // 576
#define ATILDE_W  704       // 4608 : atilde [p][l][h][64] (1/3 folded in)
#define BETAACC_N 5376      // 384
#define BETA_N    5760      // 4
#define COUNTS_N  6144      // 24576
#define OFFS_N    30720     // 24577
#define CURSOR_N  55360     // 24576
#define EIDX_N    80000     // 3000000 (750000 int4)
#define ATTNF_N   3080000   // 1536
#define FC1W_N    3081600   // 65536 (transposed [NHD][NAD])
#define FC1B_N    3147136   // 128
#define FC2W_N    3147264   // 128
#define FCW_N     3147392   // 32768 (transposed [NHD][NOD])
#define FCB_N     3180160   // 64
#define RVEC_N    3180224   // 192
#define FEATH_N   3180544   // 3200000 words = 6.4M f16 : features staged f16
#define SCORE_N   6380544   // 7200000 : S [9][NN][8] f32
#define OUTS_N    13580544  // 12582912 f32
#define NEED_WORDS 26163456UL

// ---------------- FALLBACK ws layout (round-3 proven, ~79.6 MB) -------------
#define BETAACC_F 1024
#define BETA_F    1472
#define COUNTS_F  2048
#define OFFS_F    26624
#define CURSOR_F  51264
#define ELIST_F   75904
#define FEATF_F   825920
#define ATTNF_F   7225920
#define FC1W_F    7227456
#define FC1B_F    7292992
#define FC2W_F    7293120
#define FCW_F     7293248
#define FCB_F     7326016
#define RVEC_F    7326080
#define OUTS_F    7326272

__device__ __forceinline__ float bf2f(unsigned short u) {
    union { unsigned int i; float f; } c; c.i = ((unsigned int)u) << 16; return c.f;
}

// ---------------- dtype detect ---------------------------------------------
__global__ void k_detect(const unsigned short* __restrict__ raw, int* __restrict__ flag) {
    if (threadIdx.x != 0 || blockIdx.x != 0) return;
    int wild = 0;
    for (int i = 0; i < 512; i++) {
        unsigned short u = raw[i];
        int e = (u >> 7) & 0xFF;
        if (u != 0 && (e < 0x60 || e > 0x90)) wild++;
    }
    *flag = (wild > 64) ? 1 : 0;
}

__global__ void k_cvt(const void* __restrict__ src, float* __restrict__ dst, int n,
                      const int* __restrict__ flag) {
    int i = blockIdx.x * blockDim.x + threadIdx.x;
    if (i >= n) return;
    if (*flag) dst[i] = ((const float*)src)[i];
    else       dst[i] = bf2f(((const unsigned short*)src)[i]);
}

__global__ void k_cvt_h(const void* __restrict__ src, _Float16* __restrict__ dst, int n,
                        const int* __restrict__ flag) {
    int i = blockIdx.x * blockDim.x + threadIdx.x;
    if (i >= n) return;
    float v;
    if (*flag) v = ((const float*)src)[i];
    else       v = bf2f(((const unsigned short*)src)[i]);
    dst[i] = (_Float16)v;
}

__global__ void k_cvt_tr(const void* __restrict__ src, float* __restrict__ dst,
                         int R, int C, const int* __restrict__ flag) {
    int i = blockIdx.x * blockDim.x + threadIdx.x;
    if (i >= R * C) return;
    int r = i / C, c = i % C;
    float v;
    if (*flag) v = ((const float*)src)[i];
    else       v = bf2f(((const unsigned short*)src)[i]);
    dst[c * R + r] = v;
}

// ---------------- final rotation vectors -----------------------------------
__global__ void k_finalr(const float* __restrict__ r_vec, float* __restrict__ ws) {
    int k = threadIdx.x;
    if (k >= NP * ND2) return;
    int p = k / ND2, j = k % ND2;
    float re = r_vec[(p * ND2 + j) * 2 + 0];
    float im = r_vec[(p * ND2 + j) * 2 + 1];
    float inv = rsqrtf(re * re + im * im);
    float nre = re * inv, nim = im * inv;
    float f1r = nre, f1i = -nim;                  // f[1] = conj(r)
    float f0r = f1r * nre - f1i * nim;            // f[0] = f[1]*r
    float f0i = f1r * nim + f1i * nre;
    float* fr = ws + FINALR_W + p * NL * ND2 * 2;
    fr[(0 * ND2 + j) * 2 + 0] = f0r; fr[(0 * ND2 + j) * 2 + 1] = f0i;
    fr[(1 * ND2 + j) * 2 + 0] = f1r; fr[(1 * ND2 + j) * 2 + 1] = f1i;
    fr[(2 * ND2 + j) * 2 + 0] = 1.f; fr[(2 * ND2 + j) * 2 + 1] = 0.f;
}

// ---------------- atilde[p][l][h][d] = (1/3) * cmul(at[p,h], conj(c_pl))[d] -
__global__ void k_atilde(const float* __restrict__ finalr, const float* __restrict__ attnf,
                         float* __restrict__ atil) {
    int t = blockIdx.x * 256 + threadIdx.x;
    if (t >= NP * NL * NH * IND) return;
    int d = t & 63, h = (t >> 6) & 7, l = (t >> 9) % 3, p = t / (64 * 8 * 3);
    int j = d >> 1; bool im = (d & 1) != 0;
    float cr = finalr[(p * NL * ND2 + l * ND2 + j) * 2 + 0];
    float ci = finalr[(p * NL * ND2 + l * ND2 + j) * 2 + 1];
    float ar = attnf[(p * NH + h) * IND + 2 * j];
    float ai = attnf[(p * NH + h) * IND + 2 * j + 1];
    float v = im ? (ai * cr - ar * ci) : (ar * cr + ai * ci);
    atil[t] = v * (1.f / 3.f);
}

// ---------------- per-node scores S[c][n][h], c = p*3+l ---------------------
__global__ __launch_bounds__(256) void k_score(const _Float16* __restrict__ feat,
                                               const float* __restrict__ atil,
                                               float* __restrict__ S) {
    __shared__ float xs[32][68];
    __shared__ float as[72][68];
    int t = threadIdx.x;
    int nbase = blockIdx.x * 32;
    for (int i = t; i < 72 * 64; i += 256) as[i >> 6][i & 63] = atil[i];
    for (int i = t; i < 32 * 64; i += 256)
        xs[i >> 6][i & 63] = (float)feat[(long)(nbase + (i >> 6)) * IND + (i & 63)];
    __syncthreads();
    int w = t >> 6, lane = t & 63;
    int g = lane >> 3, h = lane & 7;
    int node = w * 8 + g;  // 0..31
    float acc[9];
#pragma unroll
    for (int c = 0; c < 9; c++) acc[c] = 0.f;
    for (int ch = 0; ch < 16; ch++) {
        float4 xv = *(const float4*)&xs[node][ch * 4];
#pragma unroll
        for (int c = 0; c < 9; c++) {
            float4 av = *(const float4*)&as[c * 8 + h][ch * 4];
            acc[c] += xv.x * av.x + xv.y * av.y + xv.z * av.z + xv.w * av.w;
        }
    }
#pragma unroll
    for (int c = 0; c < 9; c++)
        S[((long)c * NN + nbase + node) * 8 + h] = acc[c];
}

// ---------------- CSR build -------------------------------------------------
__global__ void k_count(const int* __restrict__ dst, int* __restrict__ counts) {
    int id = blockIdx.x * blockDim.x + threadIdx.x;
    if (id >= NP * NE) return;
    int p = id / NE;
    atomicAdd(&counts[p * NT + dst[id]], 1);
}

__global__ void k_scan(const int* __restrict__ counts, int* __restrict__ offs,
                       int* __restrict__ cursor) {
    __shared__ int lds[257];
    int t = threadIdx.x;
    const int CH = NSEG / 256;
    int base = t * CH;
    int s = 0;
    for (int i = 0; i < CH; i++) s += counts[base + i];
    lds[t] = s;
    __syncthreads();
    if (t == 0) {
        int run = 0;
        for (int i = 0; i < 256; i++) { int v = lds[i]; lds[i] = run; run += v; }
        lds[256] = run;
    }
    __syncthreads();
    int run = lds[t];
    for (int i = 0; i < CH; i++) {
        int c = counts[base + i];
        offs[base + i] = run; cursor[base + i] = run;
        run += c;
    }
    if (t == 0) offs[NSEG] = lds[256];
}

// new: scatter expanded node triples
__global__ void k_scatter2(const int* __restrict__ dst, const int* __restrict__ indices,
                           int* __restrict__ cursor, int4* __restrict__ eidx) {
    int id = blockIdx.x * blockDim.x + threadIdx.x;
    if (id >= NP * NE) return;
    int p = id / NE, e = id % NE;
    int pos = atomicAdd(&cursor[p * NT + dst[id]], 1);
    const int* ip = indices + (long)p * NE * NL + (long)e * NL;
    eidx[pos] = make_int4(ip[0], ip[1], ip[2], 0);
}

// fallback: scatter edge id only
__global__ void k_scatter(const int* __restrict__ dst, int* __restrict__ cursor,
                          int* __restrict__ elist) {
    int id = blockIdx.x * blockDim.x + threadIdx.x;
    if (id >= NP * NE) return;
    int p = id / NE, e = id % NE;
    int pos = atomicAdd(&cursor[p * NT + dst[id]], 1);
    elist[pos] = e;
}

// ---------------- NEW edge aggregation: f16 rows, 4-deep batched MLP --------
// lane = 8*h + q handles (head h, dims d in [8q, 8q+8))
__global__ __launch_bounds__(64) void k_agg2(
        const _Float16* __restrict__ featH, const int4* __restrict__ eidx,
        const float* __restrict__ S, const float* __restrict__ finalr,
        const int* __restrict__ offs, float* __restrict__ outs) {
    int b = blockIdx.x;
    int p = b / NT;
    int t = threadIdx.x;
    int h = t >> 3, q = t & 7;

    float a0[8], a1[8], a2[8];
#pragma unroll
    for (int r = 0; r < 8; r++) { a0[r] = 0.f; a1[r] = 0.f; a2[r] = 0.f; }
    float se = 0.f;

    int beg = offs[b], end = offs[b + 1];
    const float* S0 = S + ((long)(p * 3 + 0) * NN) * 8 + h;
    const float* S1 = S + ((long)(p * 3 + 1) * NN) * 8 + h;
    const float* S2 = S + ((long)(p * 3 + 2) * NN) * 8 + h;

    int i = beg;
    // 4-deep batched main loop: all loads issued before any consumption
    for (; i + 4 <= end; i += 4) {
        int4 ee[4];
        float s0v[4], s1v[4], s2v[4];
        half8 x0[4], x1[4], x2[4];
#pragma unroll
        for (int u = 0; u < 4; u++) ee[u] = eidx[i + u];
#pragma unroll
        for (int u = 0; u < 4; u++) {
            s0v[u] = S0[(long)ee[u].x * 8];
            s1v[u] = S1[(long)ee[u].y * 8];
            s2v[u] = S2[(long)ee[u].z * 8];
            x0[u] = *(const half8*)(featH + ((long)ee[u].x << 6) + (q << 3));
            x1[u] = *(const half8*)(featH + ((long)ee[u].y << 6) + (q << 3));
            x2[u] = *(const half8*)(featH + ((long)ee[u].z << 6) + (q << 3));
        }
#pragma unroll
        for (int u = 0; u < 4; u++) {
            float s = s0v[u] + s1v[u] + s2v[u];
            float a = s > 0.f ? s : LALPHA * s;
            float eh = __expf(a);
            se += eh;
#pragma unroll
            for (int r = 0; r < 8; r++) {
                a0[r] += eh * (float)x0[u][r];
                a1[r] += eh * (float)x1[u][r];
                a2[r] += eh * (float)x2[u][r];
            }
        }
    }
    // tail
    for (; i < end; i++) {
        int4 e = eidx[i];
        float s = S0[(long)e.x * 8] + S1[(long)e.y * 8] + S2[(long)e.z * 8];
        float a = s > 0.f ? s : LALPHA * s;
        float eh = __expf(a);
        se += eh;
        half8 x0 = *(const half8*)(featH + ((long)e.x << 6) + (q << 3));
        half8 x1 = *(const half8*)(featH + ((long)e.y << 6) + (q << 3));
        half8 x2 = *(const half8*)(featH + ((long)e.z << 6) + (q << 3));
#pragma unroll
        for (int r = 0; r < 8; r++) {
            a0[r] += eh * (float)x0[r];
            a1[r] += eh * (float)x1[r];
            a2[r] += eh * (float)x2[r];
        }
    }

    // epilogue: ft = (1/3) * sum_l rot_l(acc_l) / se ; elu ; store
    const float* fr = finalr + p * NL * ND2 * 2;
    float sc = (end > beg) ? (1.f / 3.f) / se : 0.f;
    float o8[8];
#pragma unroll
    for (int jj = 0; jj < 4; jj++) {
        int j = 4 * q + jj;
        float c0r = fr[(0 * ND2 + j) * 2 + 0], c0i = fr[(0 * ND2 + j) * 2 + 1];
        float c1r = fr[(1 * ND2 + j) * 2 + 0], c1i = fr[(1 * ND2 + j) * 2 + 1];
        float ar, ai, vr, vi;
        ar = a0[2 * jj]; ai = a0[2 * jj + 1];
        vr = ar * c0r - ai * c0i; vi = ar * c0i + ai * c0r;
        ar = a1[2 * jj]; ai = a1[2 * jj + 1];
        vr += ar * c1r - ai * c1i; vi += ar * c1i + ai * c1r;
        vr += a2[2 * jj]; vi += a2[2 * jj + 1];   // l=2 rotation is identity
        vr *= sc; vi *= sc;
        o8[2 * jj]     = vr > 0.f ? vr : __expf(vr) - 1.f;
        o8[2 * jj + 1] = vi > 0.f ? vi : __expf(vi) - 1.f;
    }
    float* orow = outs + (long)b * NHD + (h << 6) + (q << 3);
    *(float4*)orow       = make_float4(o8[0], o8[1], o8[2], o8[3]);
    *(float4*)(orow + 4) = make_float4(o8[4], o8[5], o8[6], o8[7]);
}

// ---------------- FALLBACK edge aggregation (round-3 proven) ----------------
__global__ __launch_bounds__(64) void k_agg(
        const float* __restrict__ feat, const int* __restrict__ indices,
        const float* __restrict__ attn, const float* __restrict__ ws_f,
        const int* __restrict__ offs, const int* __restrict__ elist,
        float* __restrict__ outs) {
    int b = blockIdx.x;
    int p = b / NT;
    int d = threadIdx.x;
    int j = d >> 1;
    bool isim = (d & 1) != 0;
    const float* fr = ws_f + FINALR_W + p * NL * ND2 * 2;
    float cr[NL], ci[NL];
#pragma unroll
    for (int l = 0; l < NL; l++) {
        cr[l] = fr[(l * ND2 + j) * 2 + 0];
        ci[l] = fr[(l * ND2 + j) * 2 + 1];
    }
    float at[NH];
#pragma unroll
    for (int h = 0; h < NH; h++) at[h] = attn[(p * NH + h) * IND + d];
    float ft[NH], se[NH];
#pragma unroll
    for (int h = 0; h < NH; h++) { ft[h] = 0.f; se[h] = 0.f; }
    int beg = offs[b], end = offs[b + 1];
    const int* idxp = indices + (long)p * NE * NL;
    for (int i = beg; i < end; i++) {
        int e = elist[i];
        int nn[3] = { idxp[e * 3 + 0], idxp[e * 3 + 1], idxp[e * 3 + 2] };
        float hid = 0.f;
#pragma unroll
        for (int l = 0; l < NL; l++) {
            float x = feat[(long)nn[l] * IND + d];
            float xp = __shfl_xor(x, 1);
            float re = isim ? xp : x;
            float im = isim ? x : xp;
            hid += isim ? (re * ci[l] + im * cr[l]) : (re * cr[l] - im * ci[l]);
        }
        hid *= (1.f / 3.f);
#pragma unroll
        for (int h = 0; h < NH; h++) {
            float v = hid * at[h];
#pragma unroll
            for (int off = 32; off; off >>= 1) v += __shfl_xor(v, off);
            float a = v > 0.f ? v : LALPHA * v;
            float eh = __expf(a);
            se[h] += eh;
            ft[h] += eh * hid;
        }
    }
    float* orow = outs + (long)b * NHD;
    bool has = end > beg;
#pragma unroll
    for (int h = 0; h < NH; h++) {
        float v = has ? ft[h] / fmaxf(se[h], 1e-20f) : 0.f;
        v = v > 0.f ? v : (__expf(v) - 1.f);
        orow[h * IND + d] = v;
    }
}

// ---------------- fc1 -> tanh -> sum over nodes -----------------------------
__global__ __launch_bounds__(128) void k_fc1(
        const float* __restrict__ outs, const float* __restrict__ fc1_wT,
        const float* __restrict__ fc1_b, float* __restrict__ betaacc) {
    __shared__ float v[16 * NHD];
    int bx = blockIdx.x;
    int p = bx / (NT / 16);
    int n0 = (bx % (NT / 16)) * 16;
    int t = threadIdx.x;
    const float* src = outs + (long)(p * NT + n0) * NHD;
    for (int i = t; i < 16 * NHD; i += 128) v[i] = src[i];
    __syncthreads();
    float acc[16];
#pragma unroll
    for (int n = 0; n < 16; n++) acc[n] = 0.f;
    for (int k = 0; k < NHD; k++) {
        float w = fc1_wT[k * NAD + t];
#pragma unroll
        for (int n = 0; n < 16; n++) acc[n] += w * v[n * NHD + k];
    }
    float bb = fc1_b[t];
    float s = 0.f;
#pragma unroll
    for (int n = 0; n < 16; n++) s += tanhf(acc[n] + bb);
    atomicAdd(&betaacc[p * NAD + t], s);
}

__global__ void k_beta(const float* __restrict__ betaacc,
                       const float* __restrict__ fc2_w, float* __restrict__ beta) {
    __shared__ float lds[NP][NAD];
    int t = threadIdx.x;
    for (int p = 0; p < NP; p++)
        lds[p][t] = betaacc[p * NAD + t] * (1.f / NT) * fc2_w[t];
    __syncthreads();
    if (t == 0) {
        float s[NP];
        for (int p = 0; p < NP; p++) {
            s[p] = 0.f;
            for (int a = 0; a < NAD; a++) s[p] += lds[p][a];
        }
        float m = fmaxf(s[0], fmaxf(s[1], s[2]));
        float e0 = expf(s[0] - m), e1 = expf(s[1] - m), e2 = expf(s[2] - m);
        float inv = 1.f / (e0 + e1 + e2);
        beta[0] = e0 * inv; beta[1] = e1 * inv; beta[2] = e2 * inv;
    }
}

__global__ __launch_bounds__(256) void k_final(
        const float* __restrict__ outs, const float* __restrict__ beta,
        const float* __restrict__ fc_wT, const float* __restrict__ fc_b,
        void* __restrict__ outp, const int* __restrict__ flag) {
    __shared__ float h[NB * NHD];
    __shared__ float part[4 * NB * NOD];
    int n0 = blockIdx.x * NB;
    int t = threadIdx.x;
    int f = *flag;
    float b0 = beta[0], b1 = beta[1], b2 = beta[2];
    const float* o0 = outs + (long)n0 * NHD;
    for (int i = t; i < NB * NHD; i += 256) {
        float v = b0 * o0[i] + b1 * o0[(long)NT * NHD + i] + b2 * o0[2L * NT * NHD + i];
        h[i] = v;
        long idx = (long)NT * NOD + (long)n0 * NHD + i;
        if (f) ((float*)outp)[idx] = v;
        else   ((__hip_bfloat16*)outp)[idx] = __float2bfloat16(v);
    }
    __syncthreads();
    int w = t >> 6, l = t & 63;
    float acc[NB];
#pragma unroll
    for (int n = 0; n < NB; n++) acc[n] = 0.f;
    for (int k = w * 128; k < (w + 1) * 128; k++) {
        float wv = fc_wT[k * NOD + l];
#pragma unroll
        for (int n = 0; n < NB; n++) acc[n] += h[n * NHD + k] * wv;
    }
#pragma unroll
    for (int n = 0; n < NB; n++) part[(w * NB + n) * NOD + l] = acc[n];
    __syncthreads();
    for (int idx = t; idx < NB * NOD; idx += 256) {
        int n = idx >> 6, ll = idx & 63;
        float v = part[(0 * NB + n) * NOD + ll] + part[(1 * NB + n) * NOD + ll]
                + part[(2 * NB + n) * NOD + ll] + part[(3 * NB + n) * NOD + ll]
                + fc_b[ll];
        long oidx = (long)(n0 + n) * NOD + ll;
        if (f) ((float*)outp)[oidx] = v;
        else   ((__hip_bfloat16*)outp)[oidx] = __float2bfloat16(v);
    }
}

extern "C" void kernel_launch(void* const* d_in, const int* in_sizes, int n_in,
                              void* d_out, int out_size, void* d_ws, size_t ws_size,
                              hipStream_t stream) {
    const int* indices = (const int*)d_in[1];
    const int* dst     = (const int*)d_in[2];

    float* ws  = (float*)d_ws;
    int*   wsi = (int*)d_ws;

    bool big = ws_size >= NEED_WORDS * 4UL;

    // layout-dependent offsets
    const int betaacc = big ? BETAACC_N : BETAACC_F;
    const int beta    = big ? BETA_N    : BETA_F;
    const int counts  = big ? COUNTS_N  : COUNTS_F;
    const int offs    = big ? OFFS_N    : OFFS_F;
    const int cursor  = big ? CURSOR_N  : CURSOR_F;
    const int attnf   = big ? ATTNF_N   : ATTNF_F;
    const int fc1w    = big ? FC1W_N    : FC1W_F;
    const int fc1b    = big ? FC1B_N    : FC1B_F;
    const int fc2w    = big ? FC2W_N    : FC2W_F;
    const int fcw     = big ? FCW_N     : FCW_F;
    const int fcb     = big ? FCB_N     : FCB_F;
    const int rvec    = big ? RVEC_N    : RVEC_F;
    const int outsw   = big ? OUTS_N    : OUTS_F;

    hipMemsetAsync((char*)d_ws + (size_t)betaacc * 4, 0, NP * NAD * 4, stream);
    hipMemsetAsync((char*)d_ws + (size_t)counts * 4, 0, NSEG * 4, stream);

    k_detect<<<1, 1, 0, stream>>>((const unsigned short*)d_in[0], wsi + FLAG_W);

    auto cvt = [&](const void* s, int off, int n) {
        k_cvt<<<(n + 255) / 256, 256, 0, stream>>>(s, ws + off, n, wsi + FLAG_W);
    };
    cvt(d_in[3], rvec, NP * ND2 * 2);
    cvt(d_in[4], attnf, NP * NH * IND);
    k_cvt_tr<<<(NAD * NHD + 255) / 256, 256, 0, stream>>>(d_in[5], ws + fc1w,
                                                          NAD, NHD, wsi + FLAG_W);
    cvt(d_in[6], fc1b, NAD);
    cvt(d_in[7], fc2w, NAD);
    k_cvt_tr<<<(NOD * NHD + 255) / 256, 256, 0, stream>>>(d_in[8], ws + fcw,
                                                          NOD, NHD, wsi + FLAG_W);
    cvt(d_in[9], fcb, NOD);

    k_finalr<<<1, 128, 0, stream>>>(ws + rvec, ws);
    k_count<<<(NP * NE + 255) / 256, 256, 0, stream>>>(dst, wsi + counts);
    k_scan<<<1, 256, 0, stream>>>(wsi + counts, wsi + offs, wsi + cursor);

    if (big) {
        _Float16* featH = (_Float16*)(ws + FEATH_N);
        k_cvt_h<<<(NN * IND + 255) / 256, 256, 0, stream>>>(d_in[0], featH,
                                                            NN * IND, wsi + FLAG_W);
        k_atilde<<<18, 256, 0, stream>>>(ws + FINALR_W, ws + attnf, ws + ATILDE_W);
        k_score<<<NN / 32, 256, 0, stream>>>(featH, ws + ATILDE_W, ws + SCORE_N);
        k_scatter2<<<(NP * NE + 255) / 256, 256, 0, stream>>>(dst, indices,
                                                              wsi + cursor,
                                                              (int4*)(wsi + EIDX_N));
        k_agg2<<<NSEG, 64, 0, stream>>>(featH, (const int4*)(wsi + EIDX_N),
                                        ws + SCORE_N, ws + FINALR_W,
                                        wsi + offs, ws + outsw);
    } else {
        cvt(d_in[0], FEATF_F, NN * IND);
        k_scatter<<<(NP * NE + 255) / 256, 256, 0, stream>>>(dst, wsi + cursor,
                                                             wsi + ELIST_F);
        k_agg<<<NSEG, 64, 0, stream>>>(ws + FEATF_F, indices, ws + attnf, ws,
                                       wsi + offs, wsi + ELIST_F, ws + outsw);
    }

    k_fc1<<<NP * (NT / 16), 128, 0, stream>>>(ws + outsw, ws + fc1w, ws + fc1b,
                                              ws + betaacc);
    k_beta<<<1, 128, 0, stream>>>(ws + betaacc, ws + fc2w, ws + beta);
    k_final<<<NT / NB, 256, 0, stream>>>(ws + outsw, ws + beta, ws + fcw, ws + fcb,
                                         d_out, wsi + FLAG_W);
}